// Round 2
// baseline (6817.777 us; speedup 1.0000x reference)
//
#include <hip/hip_runtime.h>
#include <hip/hip_bf16.h>
#include <math.h>

// Problem constants (B=1)
#define SEQ 1024
#define DM 512
#define NH 8
#define HD 64
#define NLAYER 4
#define DIN 128
#define DFF 2048
#define DOUT 390
#define ERROWS 2047  // 2*MAXS-1

__device__ inline float block_sum(float v, float* red){
  int tid = threadIdx.x;
  red[tid] = v; __syncthreads();
  for (int s = 128; s > 0; s >>= 1){
    if (tid < s) red[tid] += red[tid + s];
    __syncthreads();
  }
  float r = red[0]; __syncthreads();
  return r;
}

__device__ inline float block_max(float v, float* red){
  int tid = threadIdx.x;
  red[tid] = v; __syncthreads();
  for (int s = 128; s > 0; s >>= 1){
    if (tid < s) red[tid] = fmaxf(red[tid], red[tid + s]);
    __syncthreads();
  }
  float r = red[0]; __syncthreads();
  return r;
}

// Generic GEMM: C[M,N] = A[M,K] @ B[K,N] + bias (+res) (gelu?)
// All fp32. M % 64 == 0, K % 16 == 0; N bounds-checked.
template<bool GELU, bool RES>
__global__ __launch_bounds__(256)
void gemm_k(const float* __restrict__ A, const float* __restrict__ B,
            const float* __restrict__ bias, const float* __restrict__ res,
            float* __restrict__ C, int M, int N, int K)
{
  __shared__ float As[16][65];
  __shared__ float Bs[16][65];
  const int tid = threadIdx.x;
  const int tx = tid & 15, ty = tid >> 4;
  const int row0 = blockIdx.y * 64, col0 = blockIdx.x * 64;

  float acc[4][4] = {};

  const int lm = tid >> 2;          // 0..63: A row within tile
  const int lk = (tid & 3) * 4;     // {0,4,8,12}: A k within tile
  const int lkB = tid >> 4;         // 0..15: B k within tile
  const int lnB = (tid & 15) * 4;   // 0..60: B col within tile

  for (int k0 = 0; k0 < K; k0 += 16) {
    const float* Ap = A + (size_t)(row0 + lm) * K + k0 + lk;
#pragma unroll
    for (int jj = 0; jj < 4; jj++) As[lk + jj][lm] = Ap[jj];
    const float* Bp = B + (size_t)(k0 + lkB) * N + col0 + lnB;
#pragma unroll
    for (int jj = 0; jj < 4; jj++) {
      int gc = col0 + lnB + jj;
      Bs[lkB][lnB + jj] = (gc < N) ? Bp[jj] : 0.f;
    }
    __syncthreads();
#pragma unroll
    for (int kk = 0; kk < 16; kk++) {
      float a[4], b[4];
#pragma unroll
      for (int i = 0; i < 4; i++) a[i] = As[kk][ty * 4 + i];
#pragma unroll
      for (int j = 0; j < 4; j++) b[j] = Bs[kk][tx * 4 + j];
#pragma unroll
      for (int i = 0; i < 4; i++)
#pragma unroll
        for (int j = 0; j < 4; j++)
          acc[i][j] += a[i] * b[j];
    }
    __syncthreads();
  }

#pragma unroll
  for (int i = 0; i < 4; i++) {
    int r = row0 + ty * 4 + i;
#pragma unroll
    for (int j = 0; j < 4; j++) {
      int c = col0 + tx * 4 + j;
      if (c < N) {
        float val = acc[i][j] + bias[c];
        if (RES) val += res[(size_t)r * N + c];
        if (GELU) val = 0.5f * val * (1.f + erff(val * 0.70710678118f));
        C[(size_t)r * N + c] = val;
      }
    }
  }
}

// LayerNorm over last dim (512), all fp32
__global__ __launch_bounds__(256)
void ln_k(const float* __restrict__ x, const float* __restrict__ g,
          const float* __restrict__ b, float* __restrict__ out)
{
  __shared__ float red[256];
  const int r = blockIdx.x, tid = threadIdx.x;
  const float* xr = x + (size_t)r * DM;
  float v0 = xr[tid], v1 = xr[tid + 256];
  float mean = block_sum(v0 + v1, red) * (1.f / DM);
  float d0 = v0 - mean, d1 = v1 - mean;
  float var = block_sum(d0 * d0 + d1 * d1, red) * (1.f / DM);
  float inv = rsqrtf(var + 1e-5f);
  out[(size_t)r * DM + tid]       = d0 * inv * g[tid]       + b[tid];
  out[(size_t)r * DM + tid + 256] = d1 * inv * g[tid + 256] + b[tid + 256];
}

// Fused attention for one (s, h): scores = q.k*scale + q.Er[s-t+S-1], softmax, o = P@V
// q,k,v,o layout: (S, DM) with head h at column h*HD. All fp32.
__global__ __launch_bounds__(256)
void attn_k(const float* __restrict__ q, const float* __restrict__ k,
            const float* __restrict__ v, const float* __restrict__ Er,
            float* __restrict__ o)
{
  __shared__ float qs[HD];
  __shared__ float p[SEQ];
  __shared__ float red[256];
  __shared__ float opart[4][HD];

  const int s = blockIdx.x, hh = blockIdx.y, tid = threadIdx.x;
  const float scale = 0.125f;  // 1/sqrt(64)

  if (tid < HD) qs[tid] = q[(size_t)s * DM + hh * HD + tid];
  __syncthreads();

  float sc[4];
#pragma unroll
  for (int it = 0; it < 4; it++) {
    int t = tid + it * 256;
    const float* krow = k + (size_t)t * DM + hh * HD;
    const float* erow = Er + (size_t)(s - t + SEQ - 1) * HD;
    float kd = 0.f, ed = 0.f;
#pragma unroll
    for (int d = 0; d < HD; d++) {
      float qd = qs[d];
      kd += qd * krow[d];
      ed += qd * erow[d];
    }
    sc[it] = kd * scale + ed;
  }

  float m = fmaxf(fmaxf(sc[0], sc[1]), fmaxf(sc[2], sc[3]));
  m = block_max(m, red);
  float lsum = 0.f;
#pragma unroll
  for (int it = 0; it < 4; it++) {
    float e = expf(sc[it] - m);
    p[tid + it * 256] = e;
    lsum += e;
  }
  float denom = block_sum(lsum, red);
  float inv = 1.f / denom;
  __syncthreads();

  // P@V: 4 groups of 64 lanes; group g covers t in [g*256, g*256+256)
  const int grp = tid >> 6, lane = tid & 63;
  float acc = 0.f;
  for (int i = 0; i < 256; i++) {
    int t = grp * 256 + i;
    acc += p[t] * v[(size_t)t * DM + hh * HD + lane];
  }
  opart[grp][lane] = acc;
  __syncthreads();
  if (tid < HD) {
    float r = (opart[0][tid] + opart[1][tid] + opart[2][tid] + opart[3][tid]) * inv;
    o[(size_t)s * DM + hh * HD + tid] = r;
  }
}

extern "C" void kernel_launch(void* const* d_in, const int* in_sizes, int n_in,
                              void* d_out, int out_size, void* d_ws, size_t ws_size,
                              hipStream_t stream) {
  const float* x     = (const float*)d_in[0];
  const float* emb_W = (const float*)d_in[1];
  const float* emb_b = (const float*)d_in[2];
  const float* Wq    = (const float*)d_in[3];
  const float* bq    = (const float*)d_in[4];
  const float* Wk    = (const float*)d_in[5];
  const float* bk    = (const float*)d_in[6];
  const float* Wv    = (const float*)d_in[7];
  const float* bv    = (const float*)d_in[8];
  const float* Wo    = (const float*)d_in[9];
  const float* bo    = (const float*)d_in[10];
  const float* Er    = (const float*)d_in[11];
  const float* ln1_g = (const float*)d_in[12];
  const float* ln1_b = (const float*)d_in[13];
  const float* W1    = (const float*)d_in[14];
  const float* b1    = (const float*)d_in[15];
  const float* W2    = (const float*)d_in[16];
  const float* b2    = (const float*)d_in[17];
  const float* ln2_g = (const float*)d_in[18];
  const float* ln2_b = (const float*)d_in[19];
  const float* lnf_g = (const float*)d_in[20];
  const float* lnf_b = (const float*)d_in[21];
  const float* Wi    = (const float*)d_in[22];
  const float* bi    = (const float*)d_in[23];
  const float* Wf    = (const float*)d_in[24];
  const float* bfin  = (const float*)d_in[25];

  // Workspace layout (floats). mid aliases the q/k/v/o region (dead by FFN).
  float* ws   = (float*)d_ws;
  float* hbuf = ws;                       // 1024*512
  float* nbuf = hbuf + SEQ * DM;          // 1024*512
  float* big  = nbuf + SEQ * DM;          // 1024*2048
  float* qbuf = big;
  float* kbuf = qbuf + SEQ * DM;
  float* vbuf = kbuf + SEQ * DM;
  float* obuf = vbuf + SEQ * DM;
  float* mid  = big;                      // aliases q/k/v/o — FFN phase only

  dim3 blk(256);
  dim3 g512(DM / 64, SEQ / 64);           // (8,16)
  dim3 gff(DFF / 64, SEQ / 64);           // (32,16)
  dim3 gwi(1024 / 64, SEQ / 64);          // (16,16)
  dim3 gout((DOUT + 63) / 64, SEQ / 64);  // (7,16)

  // Embedding: x(1024,128) @ emb_W(128,512) + emb_b -> h
  gemm_k<false, false><<<g512, blk, 0, stream>>>(
      x, emb_W, emb_b, nullptr, hbuf, SEQ, DM, DIN);

  for (int l = 0; l < NLAYER; l++) {
    const float* Wq_l = Wq + (size_t)l * DM * DM;
    const float* Wk_l = Wk + (size_t)l * DM * DM;
    const float* Wv_l = Wv + (size_t)l * DM * DM;
    const float* Wo_l = Wo + (size_t)l * DM * DM;
    const float* Er_l = Er + (size_t)l * ERROWS * HD;
    const float* W1_l = W1 + (size_t)l * DM * DFF;
    const float* W2_l = W2 + (size_t)l * DFF * DM;

    ln_k<<<SEQ, blk, 0, stream>>>(hbuf, ln1_g + l * DM, ln1_b + l * DM, nbuf);
    gemm_k<false, false><<<g512, blk, 0, stream>>>(
        nbuf, Wq_l, bq + l * DM, nullptr, qbuf, SEQ, DM, DM);
    gemm_k<false, false><<<g512, blk, 0, stream>>>(
        nbuf, Wk_l, bk + l * DM, nullptr, kbuf, SEQ, DM, DM);
    gemm_k<false, false><<<g512, blk, 0, stream>>>(
        nbuf, Wv_l, bv + l * DM, nullptr, vbuf, SEQ, DM, DM);

    attn_k<<<dim3(SEQ, NH), blk, 0, stream>>>(qbuf, kbuf, vbuf, Er_l, obuf);

    gemm_k<false, true><<<g512, blk, 0, stream>>>(
        obuf, Wo_l, bo + l * DM, hbuf, hbuf, SEQ, DM, DM);

    ln_k<<<SEQ, blk, 0, stream>>>(hbuf, ln2_g + l * DM, ln2_b + l * DM, nbuf);
    gemm_k<true, false><<<gff, blk, 0, stream>>>(
        nbuf, W1_l, b1 + l * DFF, nullptr, mid, SEQ, DFF, DM);
    gemm_k<false, true><<<g512, blk, 0, stream>>>(
        mid, W2_l, b2 + l * DM, hbuf, hbuf, SEQ, DM, DFF);
  }

  ln_k<<<SEQ, blk, 0, stream>>>(hbuf, lnf_g, lnf_b, nbuf);
  gemm_k<true, false><<<gwi, blk, 0, stream>>>(
      nbuf, Wi, bi, nullptr, mid, SEQ, 2 * DM, DM);
  gemm_k<false, false><<<gout, blk, 0, stream>>>(
      mid, Wf, bfin, nullptr, (float*)d_out, SEQ, DOUT, 2 * DM);
}

// Round 3
// 2925.474 us; speedup vs baseline: 2.3305x; 2.3305x over previous
//
#include <hip/hip_runtime.h>
#include <hip/hip_bf16.h>
#include <math.h>

// Problem constants (B=1)
#define SEQ 1024
#define DM 512
#define NH 8
#define HD 64
#define NLAYER 4
#define DIN 128
#define DFF 2048
#define DOUT 390
#define ERROWS 2047  // 2*MAXS-1

__device__ inline float block_sum(float v, float* red){
  int tid = threadIdx.x;
  red[tid] = v; __syncthreads();
  for (int s = 128; s > 0; s >>= 1){
    if (tid < s) red[tid] += red[tid + s];
    __syncthreads();
  }
  float r = red[0]; __syncthreads();
  return r;
}

__device__ inline float block_max(float v, float* red){
  int tid = threadIdx.x;
  red[tid] = v; __syncthreads();
  for (int s = 128; s > 0; s >>= 1){
    if (tid < s) red[tid] = fmaxf(red[tid], red[tid + s]);
    __syncthreads();
  }
  float r = red[0]; __syncthreads();
  return r;
}

// Generic GEMM: C[M,N] = A[M,K] @ B[K,N] (+bias) (+res) (gelu?)
// All fp32. M % 64 == 0, K % 16 == 0; N bounds-checked.
// Strided + z-batched (blockIdx.z applies sAz/sBz/sCz element offsets).
template<bool GELU, bool RES, bool BIAS>
__global__ __launch_bounds__(256)
void gemm_k(const float* __restrict__ A, const float* __restrict__ B,
            const float* __restrict__ bias, const float* __restrict__ res,
            float* __restrict__ C, int M, int N, int K,
            int lda, int ldb, int ldc,
            size_t sAz, size_t sBz, size_t sCz)
{
  __shared__ float As[16][65];
  __shared__ float Bs[16][65];
  const int tid = threadIdx.x;
  const int tx = tid & 15, ty = tid >> 4;
  const int row0 = blockIdx.y * 64, col0 = blockIdx.x * 64;
  A += blockIdx.z * sAz; B += blockIdx.z * sBz; C += blockIdx.z * sCz;

  float acc[4][4] = {};

  const int lm = tid >> 2;          // 0..63: A row within tile
  const int lk = (tid & 3) * 4;     // {0,4,8,12}: A k within tile
  const int lkB = tid >> 4;         // 0..15: B k within tile
  const int lnB = (tid & 15) * 4;   // 0..60: B col within tile

  for (int k0 = 0; k0 < K; k0 += 16) {
    const float* Ap = A + (size_t)(row0 + lm) * lda + k0 + lk;
#pragma unroll
    for (int jj = 0; jj < 4; jj++) As[lk + jj][lm] = Ap[jj];
    const float* Bp = B + (size_t)(k0 + lkB) * ldb + col0 + lnB;
#pragma unroll
    for (int jj = 0; jj < 4; jj++) {
      int gc = col0 + lnB + jj;
      Bs[lkB][lnB + jj] = (gc < N) ? Bp[jj] : 0.f;
    }
    __syncthreads();
#pragma unroll
    for (int kk = 0; kk < 16; kk++) {
      float a[4], b[4];
#pragma unroll
      for (int i = 0; i < 4; i++) a[i] = As[kk][ty * 4 + i];
#pragma unroll
      for (int j = 0; j < 4; j++) b[j] = Bs[kk][tx * 4 + j];
#pragma unroll
      for (int i = 0; i < 4; i++)
#pragma unroll
        for (int j = 0; j < 4; j++)
          acc[i][j] += a[i] * b[j];
    }
    __syncthreads();
  }

#pragma unroll
  for (int i = 0; i < 4; i++) {
    int r = row0 + ty * 4 + i;
#pragma unroll
    for (int j = 0; j < 4; j++) {
      int c = col0 + tx * 4 + j;
      if (c < N) {
        float val = acc[i][j];
        if (BIAS) val += bias[c];
        if (RES) val += res[(size_t)r * ldc + c];
        if (GELU) val = 0.5f * val * (1.f + erff(val * 0.70710678118f));
        C[(size_t)r * ldc + c] = val;
      }
    }
  }
}

// LayerNorm over last dim (512), all fp32
__global__ __launch_bounds__(256)
void ln_k(const float* __restrict__ x, const float* __restrict__ g,
          const float* __restrict__ b, float* __restrict__ out)
{
  __shared__ float red[256];
  const int r = blockIdx.x, tid = threadIdx.x;
  const float* xr = x + (size_t)r * DM;
  float v0 = xr[tid], v1 = xr[tid + 256];
  float mean = block_sum(v0 + v1, red) * (1.f / DM);
  float d0 = v0 - mean, d1 = v1 - mean;
  float var = block_sum(d0 * d0 + d1 * d1, red) * (1.f / DM);
  float inv = rsqrtf(var + 1e-5f);
  out[(size_t)r * DM + tid]       = d0 * inv * g[tid]       + b[tid];
  out[(size_t)r * DM + tid + 256] = d1 * inv * g[tid + 256] + b[tid + 256];
}

// Scores: sc[h][s][t] = (q_s . k_t)*scale + q_s . Er[s-t+1023]
// 64x64 output tile per block; q/k head-block and the 127-row Er diagonal
// band staged in LDS. Toeplitz fusion: acc += a[i]*(b[j] + e[i-j+3]).
__global__ __launch_bounds__(256)
void scores_k(const float* __restrict__ q, const float* __restrict__ k,
              const float* __restrict__ Er, float* __restrict__ sc)
{
  __shared__ float As[HD][65];    // [d][si]
  __shared__ float Bs[HD][65];    // [d][tj]  (pre-scaled by 0.125)
  __shared__ float Es[127][65];   // [band row][d]

  const int tid = threadIdx.x;
  const int t0 = blockIdx.x * 64, s0 = blockIdx.y * 64, hh = blockIdx.z;

  {
    const int rr = tid >> 2, db = (tid & 3) * 16;
    const float* qp = q + (size_t)(s0 + rr) * DM + hh * HD + db;
    const float* kp = k + (size_t)(t0 + rr) * DM + hh * HD + db;
#pragma unroll
    for (int j = 0; j < 16; j++) {
      As[db + j][rr] = qp[j];
      Bs[db + j][rr] = kp[j] * 0.125f;
    }
    const int rb = s0 - t0 + 960;   // band base; rb in [0,1920], rb+126 <= 2046
    for (int idx = tid; idx < 127 * 16; idx += 256) {
      int r = idx >> 4, dc = (idx & 15) * 4;
      const float* ep = Er + (size_t)(rb + r) * HD + dc;
#pragma unroll
      for (int j = 0; j < 4; j++) Es[r][dc + j] = ep[j];
    }
  }
  __syncthreads();

  const int tx = tid & 15, ty = tid >> 4;
  const int base = ty * 4 - tx * 4 + 60;  // Es row for (i-j)=-3
  float acc[4][4] = {};

#pragma unroll 4
  for (int kk = 0; kk < HD; kk++) {
    float a[4], b[4], e[7];
#pragma unroll
    for (int i = 0; i < 4; i++) a[i] = As[kk][ty * 4 + i];
#pragma unroll
    for (int j = 0; j < 4; j++) b[j] = Bs[kk][tx * 4 + j];
#pragma unroll
    for (int dd = 0; dd < 7; dd++) e[dd] = Es[base + dd][kk];
#pragma unroll
    for (int i = 0; i < 4; i++)
#pragma unroll
      for (int j = 0; j < 4; j++)
        acc[i][j] += a[i] * (b[j] + e[i - j + 3]);
  }

  float* out = sc + (size_t)hh * SEQ * SEQ;
#pragma unroll
  for (int i = 0; i < 4; i++) {
    int s = s0 + ty * 4 + i;
#pragma unroll
    for (int j = 0; j < 4; j++)
      out[(size_t)s * SEQ + t0 + tx * 4 + j] = acc[i][j];
  }
}

// Row softmax in-place over sc[h][s][0..SEQ)
__global__ __launch_bounds__(256)
void softmax_k(float* __restrict__ sc)
{
  __shared__ float red[256];
  const int s = blockIdx.x, hh = blockIdx.y, tid = threadIdx.x;
  float* row = sc + (size_t)hh * SEQ * SEQ + (size_t)s * SEQ;
  float v[4];
#pragma unroll
  for (int it = 0; it < 4; it++) v[it] = row[tid + it * 256];
  float m = fmaxf(fmaxf(v[0], v[1]), fmaxf(v[2], v[3]));
  m = block_max(m, red);
  float lsum = 0.f;
#pragma unroll
  for (int it = 0; it < 4; it++) { v[it] = expf(v[it] - m); lsum += v[it]; }
  float inv = 1.f / block_sum(lsum, red);
#pragma unroll
  for (int it = 0; it < 4; it++) row[tid + it * 256] = v[it] * inv;
}

extern "C" void kernel_launch(void* const* d_in, const int* in_sizes, int n_in,
                              void* d_out, int out_size, void* d_ws, size_t ws_size,
                              hipStream_t stream) {
  const float* x     = (const float*)d_in[0];
  const float* emb_W = (const float*)d_in[1];
  const float* emb_b = (const float*)d_in[2];
  const float* Wq    = (const float*)d_in[3];
  const float* bq    = (const float*)d_in[4];
  const float* Wk    = (const float*)d_in[5];
  const float* bk    = (const float*)d_in[6];
  const float* Wv    = (const float*)d_in[7];
  const float* bv    = (const float*)d_in[8];
  const float* Wo    = (const float*)d_in[9];
  const float* bo    = (const float*)d_in[10];
  const float* Er    = (const float*)d_in[11];
  const float* ln1_g = (const float*)d_in[12];
  const float* ln1_b = (const float*)d_in[13];
  const float* W1    = (const float*)d_in[14];
  const float* b1    = (const float*)d_in[15];
  const float* W2    = (const float*)d_in[16];
  const float* b2    = (const float*)d_in[17];
  const float* ln2_g = (const float*)d_in[18];
  const float* ln2_b = (const float*)d_in[19];
  const float* lnf_g = (const float*)d_in[20];
  const float* lnf_b = (const float*)d_in[21];
  const float* Wi    = (const float*)d_in[22];
  const float* bi    = (const float*)d_in[23];
  const float* Wf    = (const float*)d_in[24];
  const float* bfin  = (const float*)d_in[25];

  // Workspace (floats): hbuf(2MB) nbuf(2MB) q/k/v/o(8MB) sc(32MB, aliased by mid)
  float* ws   = (float*)d_ws;
  float* hbuf = ws;                       // 1024*512
  float* nbuf = hbuf + SEQ * DM;          // 1024*512
  float* qbuf = nbuf + SEQ * DM;
  float* kbuf = qbuf + SEQ * DM;
  float* vbuf = kbuf + SEQ * DM;
  float* obuf = vbuf + SEQ * DM;
  float* scb  = obuf + SEQ * DM;          // 8*1024*1024 (scores/probs)
  float* mid  = scb;                      // aliases sc — FFN phase only

  dim3 blk(256);
  dim3 g512(DM / 64, SEQ / 64);           // (8,16)
  dim3 gff(DFF / 64, SEQ / 64);           // (32,16)
  dim3 gwi(1024 / 64, SEQ / 64);          // (16,16)
  dim3 gout((DOUT + 63) / 64, SEQ / 64);  // (7,16)
  dim3 gsc(SEQ / 64, SEQ / 64, NH);       // (16,16,8)
  dim3 gsm(SEQ, NH);
  dim3 gpv(1, SEQ / 64, NH);              // (1,16,8)

  // Embedding: x(1024,128) @ emb_W(128,512) + emb_b -> h
  gemm_k<false, false, true><<<g512, blk, 0, stream>>>(
      x, emb_W, emb_b, nullptr, hbuf, SEQ, DM, DIN, DIN, DM, DM, 0, 0, 0);

  for (int l = 0; l < NLAYER; l++) {
    const float* Wq_l = Wq + (size_t)l * DM * DM;
    const float* Wk_l = Wk + (size_t)l * DM * DM;
    const float* Wv_l = Wv + (size_t)l * DM * DM;
    const float* Wo_l = Wo + (size_t)l * DM * DM;
    const float* Er_l = Er + (size_t)l * ERROWS * HD;
    const float* W1_l = W1 + (size_t)l * DM * DFF;
    const float* W2_l = W2 + (size_t)l * DFF * DM;

    ln_k<<<SEQ, blk, 0, stream>>>(hbuf, ln1_g + l * DM, ln1_b + l * DM, nbuf);
    gemm_k<false, false, true><<<g512, blk, 0, stream>>>(
        nbuf, Wq_l, bq + l * DM, nullptr, qbuf, SEQ, DM, DM, DM, DM, DM, 0, 0, 0);
    gemm_k<false, false, true><<<g512, blk, 0, stream>>>(
        nbuf, Wk_l, bk + l * DM, nullptr, kbuf, SEQ, DM, DM, DM, DM, DM, 0, 0, 0);
    gemm_k<false, false, true><<<g512, blk, 0, stream>>>(
        nbuf, Wv_l, bv + l * DM, nullptr, vbuf, SEQ, DM, DM, DM, DM, DM, 0, 0, 0);

    scores_k<<<gsc, blk, 0, stream>>>(qbuf, kbuf, Er_l, scb);
    softmax_k<<<gsm, blk, 0, stream>>>(scb);
    // o_h = P_h @ V_h  (z-batched over heads)
    gemm_k<false, false, false><<<gpv, blk, 0, stream>>>(
        scb, vbuf + 0, nullptr, nullptr, obuf, SEQ, HD, SEQ,
        SEQ, DM, DM, (size_t)SEQ * SEQ, HD, HD);

    gemm_k<false, true, true><<<g512, blk, 0, stream>>>(
        obuf, Wo_l, bo + l * DM, hbuf, hbuf, SEQ, DM, DM, DM, DM, DM, 0, 0, 0);

    ln_k<<<SEQ, blk, 0, stream>>>(hbuf, ln2_g + l * DM, ln2_b + l * DM, nbuf);
    gemm_k<true, false, true><<<gff, blk, 0, stream>>>(
        nbuf, W1_l, b1 + l * DFF, nullptr, mid, SEQ, DFF, DM, DM, DFF, DFF, 0, 0, 0);
    gemm_k<false, true, true><<<g512, blk, 0, stream>>>(
        mid, W2_l, b2 + l * DM, hbuf, hbuf, SEQ, DM, DFF, DFF, DM, DM, 0, 0, 0);
  }

  ln_k<<<SEQ, blk, 0, stream>>>(hbuf, lnf_g, lnf_b, nbuf);
  gemm_k<true, false, true><<<gwi, blk, 0, stream>>>(
      nbuf, Wi, bi, nullptr, mid, SEQ, 2 * DM, DM, DM, 2 * DM, 2 * DM, 0, 0, 0);
  gemm_k<false, false, true><<<gout, blk, 0, stream>>>(
      mid, Wf, bfin, nullptr, (float*)d_out, SEQ, DOUT, 2 * DM, 2 * DM, DOUT, DOUT, 0, 0, 0);
}

// Round 4
// 789.826 us; speedup vs baseline: 8.6320x; 3.7039x over previous
//
#include <hip/hip_runtime.h>
#include <hip/hip_bf16.h>
#include <math.h>

// Problem constants (B=1)
#define SEQ 1024
#define DM 512
#define NH 8
#define HD 64
#define NLAYER 4
#define DIN 128
#define DFF 2048
#define DOUT 390
#define ERROWS 2047  // 2*MAXS-1

using u16 = unsigned short;
typedef __attribute__((ext_vector_type(8))) short short8;
typedef __attribute__((ext_vector_type(4))) float f32x4;

__device__ inline u16 f2bf(float f){
  __hip_bfloat16 h = __float2bfloat16(f);
  return *(u16*)&h;
}
__device__ inline float bf2f(u16 u){
  __hip_bfloat16 h; *(u16*)&h = u;
  return __bfloat162float(h);
}

__device__ inline float block_sum(float v, float* red){
  int tid = threadIdx.x;
  red[tid] = v; __syncthreads();
  for (int s = 128; s > 0; s >>= 1){
    if (tid < s) red[tid] += red[tid + s];
    __syncthreads();
  }
  float r = red[0]; __syncthreads();
  return r;
}
__device__ inline float block_max(float v, float* red){
  int tid = threadIdx.x;
  red[tid] = v; __syncthreads();
  for (int s = 128; s > 0; s >>= 1){
    if (tid < s) red[tid] = fmaxf(red[tid], red[tid + s]);
    __syncthreads();
  }
  float r = red[0]; __syncthreads();
  return r;
}

// ---------- weight prep ----------
// plain fp32 -> bf16 convert (n multiple of 4)
__global__ __launch_bounds__(256)
void cvt_k(const float* __restrict__ src, u16* __restrict__ dst, int n){
  int i = (blockIdx.x * 256 + threadIdx.x) * 4;
  if (i < n){
    float4 v = *(const float4*)(src + i);
    dst[i+0] = f2bf(v.x); dst[i+1] = f2bf(v.y);
    dst[i+2] = f2bf(v.z); dst[i+3] = f2bf(v.w);
  }
}

// transpose + convert: WT[n][k] = bf16(W[k][n]); K,Npad mult of 64; rows n>=N zero-filled
__global__ __launch_bounds__(256)
void wt_k(const float* __restrict__ W, u16* __restrict__ WT, int K, int N, int Npad){
  __shared__ float Ls[64][65];
  W  += (size_t)blockIdx.z * K * N;
  WT += (size_t)blockIdx.z * Npad * K;
  const int k0 = blockIdx.x * 64, n0 = blockIdx.y * 64;
  const int t = threadIdx.x;
  const int cr = (t & 15) * 4, rr0 = t >> 4;
#pragma unroll
  for (int rr = 0; rr < 4; rr++){
    int row = rr0 + rr * 16;
    const float* wp = W + (size_t)(k0 + row) * N + n0 + cr;
#pragma unroll
    for (int j = 0; j < 4; j++)
      Ls[row][cr + j] = (n0 + cr + j < N) ? wp[j] : 0.f;
  }
  __syncthreads();
  const int nrow = t >> 2, kc = (t & 3) * 16;
  const bool valid = (n0 + nrow) < N;
  u16 buf[16];
#pragma unroll
  for (int j = 0; j < 16; j++)
    buf[j] = valid ? f2bf(Ls[kc + j][nrow]) : (u16)0;
  u16* out = WT + (size_t)(n0 + nrow) * K + k0 + kc;
  ((uint4*)out)[0] = ((uint4*)buf)[0];
  ((uint4*)out)[1] = ((uint4*)buf)[1];
}

// ---------- MFMA GEMM ----------
// C[M,N] = A[M,K] @ B + epilogue.  A bf16 row-major [M][K] (lda).
// BTRANS: B is pre-transposed bf16 [Npad][K] (ldb=K). else B is bf16 [K][N] (ldb).
// M mult 64, K mult 32. N guarded. z-batched via element strides.
template<bool GELU, bool RES, bool BIAS, bool OUTBF, bool BTRANS>
__global__ __launch_bounds__(256)
void mgemm(const u16* __restrict__ A, const u16* __restrict__ B,
           const float* __restrict__ bias, const float* __restrict__ res,
           void* __restrict__ Cout, int M, int N, int K,
           int lda, int ldb, int ldc,
           long sAz, long sBz, long sCz)
{
  __shared__ u16 As[64][40];
  __shared__ u16 Bs[64][40];
  const int tid = threadIdx.x;
  A += (long)blockIdx.z * sAz;
  B += (long)blockIdx.z * sBz;
  const int row0 = blockIdx.y * 64, n0 = blockIdx.x * 64;
  const int w = tid >> 6, lane = tid & 63, m = lane & 15, quad = lane >> 4;

  f32x4 acc[4];
#pragma unroll
  for (int c = 0; c < 4; c++) acc[c] = (f32x4){0.f, 0.f, 0.f, 0.f};

  const int ar = tid >> 2, akc = (tid & 3) * 8;   // A staging
  const int bnr = tid >> 2, bkc = (tid & 3) * 8;  // B staging (BTRANS)
  const int bkr = tid >> 3, bnc = (tid & 7) * 8;  // B staging (!BTRANS)

  for (int k0 = 0; k0 < K; k0 += 32){
    *(uint4*)&As[ar][akc] = *(const uint4*)&A[(long)(row0 + ar) * lda + k0 + akc];
    if (BTRANS){
      *(uint4*)&Bs[bnr][bkc] = *(const uint4*)&B[(long)(n0 + bnr) * ldb + k0 + bkc];
    } else {
      uint4 v = *(const uint4*)&B[(long)(k0 + bkr) * ldb + n0 + bnc];
      const u16* pv = (const u16*)&v;
#pragma unroll
      for (int j = 0; j < 8; j++) Bs[bnc + j][bkr] = pv[j];
    }
    __syncthreads();
    short8 a = *(const short8*)&As[w * 16 + m][quad * 8];
#pragma unroll
    for (int c = 0; c < 4; c++){
      short8 b = *(const short8*)&Bs[c * 16 + m][quad * 8];
      acc[c] = __builtin_amdgcn_mfma_f32_16x16x32_bf16(a, b, acc[c], 0, 0, 0);
    }
    __syncthreads();
  }

#pragma unroll
  for (int c = 0; c < 4; c++){
    int col = n0 + c * 16 + m;
    if (col < N){
#pragma unroll
      for (int r = 0; r < 4; r++){
        int row = row0 + w * 16 + quad * 4 + r;
        float val = acc[c][r];
        if (BIAS) val += bias[col];
        if (RES)  val += res[(long)row * ldc + col];
        if (GELU) val = 0.5f * val * (1.f + erff(val * 0.70710678118f));
        if (OUTBF) ((u16*)Cout)[(long)blockIdx.z * sCz + (long)row * ldc + col] = f2bf(val);
        else      ((float*)Cout)[(long)blockIdx.z * sCz + (long)row * ldc + col] = val;
      }
    }
  }
}

// ---------- LayerNorm: fp32 in, bf16 out ----------
__global__ __launch_bounds__(256)
void ln_k(const float* __restrict__ x, const float* __restrict__ g,
          const float* __restrict__ b, u16* __restrict__ out)
{
  __shared__ float red[256];
  const int r = blockIdx.x, tid = threadIdx.x;
  const float* xr = x + (size_t)r * DM;
  float v0 = xr[tid], v1 = xr[tid + 256];
  float mean = block_sum(v0 + v1, red) * (1.f / DM);
  float d0 = v0 - mean, d1 = v1 - mean;
  float var = block_sum(d0 * d0 + d1 * d1, red) * (1.f / DM);
  float inv = rsqrtf(var + 1e-5f);
  out[(size_t)r * DM + tid]       = f2bf(d0 * inv * g[tid]       + b[tid]);
  out[(size_t)r * DM + tid + 256] = f2bf(d1 * inv * g[tid + 256] + b[tid + 256]);
}

// ---------- scores: MFMA QK^T + Toeplitz rel term ----------
// sc[h][s][t] = 0.125*(q_s.k_t) + q_s.Er[s-t+1023]
__global__ __launch_bounds__(256)
void scores_k(const u16* __restrict__ q, const u16* __restrict__ k,
              const u16* __restrict__ ErB, float* __restrict__ sc)
{
  __shared__ u16 Qs[64][72];
  __shared__ u16 Ks[64][72];
  __shared__ u16 Es[128][72];
  __shared__ u16 Ts[64][136];

  const int tid = threadIdx.x;
  const int t0 = blockIdx.x * 64, s0 = blockIdx.y * 64, hh = blockIdx.z;
  const int rb = s0 - t0 + 960;  // Er band base: rows rb..rb+126, all in [0,2046]

  {
    const int r = tid >> 2, kc = (tid & 3) * 16;
    const u16* qp = q + (size_t)(s0 + r) * DM + hh * HD + kc;
    const u16* kp = k + (size_t)(t0 + r) * DM + hh * HD + kc;
    *(uint4*)&Qs[r][kc]     = *(const uint4*)&qp[0];
    *(uint4*)&Qs[r][kc + 8] = *(const uint4*)&qp[8];
    *(uint4*)&Ks[r][kc]     = *(const uint4*)&kp[0];
    *(uint4*)&Ks[r][kc + 8] = *(const uint4*)&kp[8];
    for (int idx = tid; idx < 127 * 8; idx += 256){
      int er = idx >> 3, ekc = (idx & 7) * 8;
      *(uint4*)&Es[er][ekc] = *(const uint4*)&ErB[(size_t)(rb + er) * HD + ekc];
    }
    if (tid < 8){ uint4 z = {0,0,0,0}; *(uint4*)&Es[127][tid * 8] = z; }
  }
  __syncthreads();

  const int w = tid >> 6, lane = tid & 63, m = lane & 15, quad = lane >> 4;
  short8 a0 = *(const short8*)&Qs[w * 16 + m][quad * 8];
  short8 a1 = *(const short8*)&Qs[w * 16 + m][32 + quad * 8];

  f32x4 qk[4], tt[8];
#pragma unroll
  for (int c = 0; c < 4; c++) qk[c] = (f32x4){0.f,0.f,0.f,0.f};
#pragma unroll
  for (int c = 0; c < 8; c++) tt[c] = (f32x4){0.f,0.f,0.f,0.f};

#pragma unroll
  for (int c = 0; c < 4; c++){
    short8 b0 = *(const short8*)&Ks[c * 16 + m][quad * 8];
    short8 b1 = *(const short8*)&Ks[c * 16 + m][32 + quad * 8];
    qk[c] = __builtin_amdgcn_mfma_f32_16x16x32_bf16(a0, b0, qk[c], 0, 0, 0);
    qk[c] = __builtin_amdgcn_mfma_f32_16x16x32_bf16(a1, b1, qk[c], 0, 0, 0);
  }
#pragma unroll
  for (int c = 0; c < 8; c++){
    short8 b0 = *(const short8*)&Es[c * 16 + m][quad * 8];
    short8 b1 = *(const short8*)&Es[c * 16 + m][32 + quad * 8];
    tt[c] = __builtin_amdgcn_mfma_f32_16x16x32_bf16(a0, b0, tt[c], 0, 0, 0);
    tt[c] = __builtin_amdgcn_mfma_f32_16x16x32_bf16(a1, b1, tt[c], 0, 0, 0);
  }

  // T -> LDS (bf16), then gather T[i][i-j+63]
#pragma unroll
  for (int c = 0; c < 8; c++)
#pragma unroll
    for (int r = 0; r < 4; r++)
      Ts[w * 16 + quad * 4 + r][c * 16 + m] = f2bf(tt[c][r]);
  __syncthreads();

  float* out = sc + ((size_t)hh * SEQ + s0) * SEQ + t0;
#pragma unroll
  for (int c = 0; c < 4; c++){
    int j = c * 16 + m;
#pragma unroll
    for (int r = 0; r < 4; r++){
      int i = w * 16 + quad * 4 + r;
      float val = qk[c][r] * 0.125f + bf2f(Ts[i][i - j + 63]);
      out[(size_t)i * SEQ + j] = val;
    }
  }
}

// ---------- softmax: fp32 scores -> bf16 probs, in place ----------
__global__ __launch_bounds__(256)
void softmax_k(float* __restrict__ sc)
{
  __shared__ float red[256];
  const int s = blockIdx.x, hh = blockIdx.y, tid = threadIdx.x;
  float* rowf = sc + ((size_t)hh * SEQ + s) * SEQ;
  u16* rowb = (u16*)rowf;
  float v[4];
#pragma unroll
  for (int it = 0; it < 4; it++) v[it] = rowf[tid + it * 256];
  float mx = fmaxf(fmaxf(v[0], v[1]), fmaxf(v[2], v[3]));
  mx = block_max(mx, red);
  float lsum = 0.f;
#pragma unroll
  for (int it = 0; it < 4; it++){ v[it] = expf(v[it] - mx); lsum += v[it]; }
  float inv = 1.f / block_sum(lsum, red);
#pragma unroll
  for (int it = 0; it < 4; it++) rowb[tid + it * 256] = f2bf(v[it] * inv);
}

extern "C" void kernel_launch(void* const* d_in, const int* in_sizes, int n_in,
                              void* d_out, int out_size, void* d_ws, size_t ws_size,
                              hipStream_t stream) {
  const float* x     = (const float*)d_in[0];
  const float* emb_W = (const float*)d_in[1];
  const float* emb_b = (const float*)d_in[2];
  const float* Wq    = (const float*)d_in[3];
  const float* bq    = (const float*)d_in[4];
  const float* Wk    = (const float*)d_in[5];
  const float* bk    = (const float*)d_in[6];
  const float* Wv    = (const float*)d_in[7];
  const float* bv    = (const float*)d_in[8];
  const float* Wo    = (const float*)d_in[9];
  const float* bo    = (const float*)d_in[10];
  const float* Er    = (const float*)d_in[11];
  const float* ln1_g = (const float*)d_in[12];
  const float* ln1_b = (const float*)d_in[13];
  const float* W1    = (const float*)d_in[14];
  const float* b1    = (const float*)d_in[15];
  const float* W2    = (const float*)d_in[16];
  const float* b2    = (const float*)d_in[17];
  const float* ln2_g = (const float*)d_in[18];
  const float* ln2_b = (const float*)d_in[19];
  const float* lnf_g = (const float*)d_in[20];
  const float* lnf_b = (const float*)d_in[21];
  const float* Wi    = (const float*)d_in[22];
  const float* bi    = (const float*)d_in[23];
  const float* Wf    = (const float*)d_in[24];
  const float* bfin  = (const float*)d_in[25];

  // ---- workspace carve (bf16 region first, fp32 region after) ----
  u16* p = (u16*)d_ws;
  u16* xb   = p; p += SEQ * DIN;                 // 1024*128
  u16* embT = p; p += DM * DIN;                  // [512][128]
  u16* wqT  = p; p += (size_t)NLAYER * DM * DM;
  u16* wkT  = p; p += (size_t)NLAYER * DM * DM;
  u16* wvT  = p; p += (size_t)NLAYER * DM * DM;
  u16* woT  = p; p += (size_t)NLAYER * DM * DM;
  u16* w1T  = p; p += (size_t)NLAYER * DFF * DM;   // [2048][512] per layer
  u16* w2T  = p; p += (size_t)NLAYER * DM * DFF;   // [512][2048] per layer
  u16* wiT  = p; p += (size_t)(2 * DM) * DM;       // [1024][512]
  u16* wfT  = p; p += (size_t)448 * (2 * DM);      // [448][1024], pad of 390
  u16* erB  = p; p += (size_t)NLAYER * ERROWS * HD;
  u16* nb   = p; p += SEQ * DM;
  u16* qb   = p; p += SEQ * DM;
  u16* kb   = p; p += SEQ * DM;
  u16* vb   = p; p += SEQ * DM;
  u16* ob   = p; p += SEQ * DM;
  float* hb  = (float*)p;                         // 1024*512 fp32
  float* scb = hb + SEQ * DM;                     // 8*1024*1024 fp32 (scores/probs/mid)
  u16* mid   = (u16*)scb;                         // FFN intermediate (aliases scores)

  dim3 blk(256);

  // ---- one-time conversions ----
  cvt_k<<<SEQ * DIN / 4 / 256, blk, 0, stream>>>(x, xb, SEQ * DIN);
  cvt_k<<<(NLAYER * ERROWS * HD / 4 + 255) / 256, blk, 0, stream>>>(Er, erB, NLAYER * ERROWS * HD);
  wt_k<<<dim3(DIN / 64, DM / 64, 1), blk, 0, stream>>>(emb_W, embT, DIN, DM, DM);
  wt_k<<<dim3(DM / 64, DM / 64, NLAYER), blk, 0, stream>>>(Wq, wqT, DM, DM, DM);
  wt_k<<<dim3(DM / 64, DM / 64, NLAYER), blk, 0, stream>>>(Wk, wkT, DM, DM, DM);
  wt_k<<<dim3(DM / 64, DM / 64, NLAYER), blk, 0, stream>>>(Wv, wvT, DM, DM, DM);
  wt_k<<<dim3(DM / 64, DM / 64, NLAYER), blk, 0, stream>>>(Wo, woT, DM, DM, DM);
  wt_k<<<dim3(DM / 64, DFF / 64, NLAYER), blk, 0, stream>>>(W1, w1T, DM, DFF, DFF);
  wt_k<<<dim3(DFF / 64, DM / 64, NLAYER), blk, 0, stream>>>(W2, w2T, DFF, DM, DM);
  wt_k<<<dim3(DM / 64, 2 * DM / 64, 1), blk, 0, stream>>>(Wi, wiT, DM, 2 * DM, 2 * DM);
  wt_k<<<dim3(2 * DM / 64, 448 / 64, 1), blk, 0, stream>>>(Wf, wfT, 2 * DM, DOUT, 448);

  dim3 g512(8, 16), gff(32, 16), gwi(16, 16), gout(7, 16);
  dim3 gsc(16, 16, NH), gsm(SEQ, NH), gpv(1, 16, NH);

  // ---- embedding ----
  mgemm<false, false, true, false, true><<<g512, blk, 0, stream>>>(
      xb, embT, emb_b, nullptr, hb, SEQ, DM, DIN, DIN, DIN, DM, 0, 0, 0);

  for (int l = 0; l < NLAYER; l++) {
    const u16* wqT_l = wqT + (size_t)l * DM * DM;
    const u16* wkT_l = wkT + (size_t)l * DM * DM;
    const u16* wvT_l = wvT + (size_t)l * DM * DM;
    const u16* woT_l = woT + (size_t)l * DM * DM;
    const u16* w1T_l = w1T + (size_t)l * DFF * DM;
    const u16* w2T_l = w2T + (size_t)l * DM * DFF;
    const u16* erB_l = erB + (size_t)l * ERROWS * HD;

    ln_k<<<SEQ, blk, 0, stream>>>(hb, ln1_g + l * DM, ln1_b + l * DM, nb);
    mgemm<false, false, true, true, true><<<g512, blk, 0, stream>>>(
        nb, wqT_l, bq + l * DM, nullptr, qb, SEQ, DM, DM, DM, DM, DM, 0, 0, 0);
    mgemm<false, false, true, true, true><<<g512, blk, 0, stream>>>(
        nb, wkT_l, bk + l * DM, nullptr, kb, SEQ, DM, DM, DM, DM, DM, 0, 0, 0);
    mgemm<false, false, true, true, true><<<g512, blk, 0, stream>>>(
        nb, wvT_l, bv + l * DM, nullptr, vb, SEQ, DM, DM, DM, DM, DM, 0, 0, 0);

    scores_k<<<gsc, blk, 0, stream>>>(qb, kb, erB_l, scb);
    softmax_k<<<gsm, blk, 0, stream>>>(scb);

    // O_h = P_h @ V_h  (z over heads). probs rows: 2048 u16 stride (bf16 in fp32 rows)
    mgemm<false, false, false, true, false><<<gpv, blk, 0, stream>>>(
        (const u16*)scb, vb, nullptr, nullptr, ob, SEQ, HD, SEQ,
        2 * SEQ, DM, DM, (long)SEQ * 2 * SEQ, HD, HD);

    mgemm<false, true, true, false, true><<<g512, blk, 0, stream>>>(
        ob, woT_l, bo + l * DM, hb, hb, SEQ, DM, DM, DM, DM, DM, 0, 0, 0);

    ln_k<<<SEQ, blk, 0, stream>>>(hb, ln2_g + l * DM, ln2_b + l * DM, nb);
    mgemm<true, false, true, true, true><<<gff, blk, 0, stream>>>(
        nb, w1T_l, b1 + l * DFF, nullptr, mid, SEQ, DFF, DM, DM, DM, DFF, 0, 0, 0);
    mgemm<false, true, true, false, true><<<g512, blk, 0, stream>>>(
        mid, w2T_l, b2 + l * DM, hb, hb, SEQ, DM, DFF, DFF, DFF, DM, 0, 0, 0);
  }

  ln_k<<<SEQ, blk, 0, stream>>>(hb, lnf_g, lnf_b, nb);
  mgemm<true, false, true, true, true><<<gwi, blk, 0, stream>>>(
      nb, wiT, bi, nullptr, mid, SEQ, 2 * DM, DM, DM, DM, 2 * DM, 0, 0, 0);
  mgemm<false, false, true, false, true><<<gout, blk, 0, stream>>>(
      mid, wfT, bfin, nullptr, (float*)d_out, SEQ, DOUT, 2 * DM, 2 * DM, 2 * DM, DOUT, 0, 0, 0);
}

// Round 5
// 706.998 us; speedup vs baseline: 9.6433x; 1.1172x over previous
//
#include <hip/hip_runtime.h>
#include <hip/hip_bf16.h>
#include <math.h>

// Problem constants (B=1)
#define SEQ 1024
#define DM 512
#define NH 8
#define HD 64
#define NLAYER 4
#define DIN 128
#define DFF 2048
#define DOUT 390
#define ERROWS 2047  // 2*MAXS-1

using u16 = unsigned short;
typedef __attribute__((ext_vector_type(8))) short short8;
typedef __attribute__((ext_vector_type(4))) float f32x4;

__device__ inline u16 f2bf(float f){
  __hip_bfloat16 h = __float2bfloat16(f);
  return *(u16*)&h;
}
__device__ inline float bf2f(u16 u){
  __hip_bfloat16 h; *(u16*)&h = u;
  return __bfloat162float(h);
}

__device__ inline float block_sum(float v, float* red){
  int tid = threadIdx.x;
  red[tid] = v; __syncthreads();
  for (int s = 128; s > 0; s >>= 1){
    if (tid < s) red[tid] += red[tid + s];
    __syncthreads();
  }
  float r = red[0]; __syncthreads();
  return r;
}

// ---------- weight prep ----------
// plain fp32 -> bf16 convert (n multiple of 4)
__global__ __launch_bounds__(256)
void cvt_k(const float* __restrict__ src, u16* __restrict__ dst, int n){
  int i = (blockIdx.x * 256 + threadIdx.x) * 4;
  if (i < n){
    float4 v = *(const float4*)(src + i);
    dst[i+0] = f2bf(v.x); dst[i+1] = f2bf(v.y);
    dst[i+2] = f2bf(v.z); dst[i+3] = f2bf(v.w);
  }
}

// transpose + convert: WT[n][k] = bf16(W[k][n]); K mult 64; rows n>=N zero-filled
// z-batched with explicit element strides zSrc/zDst.
__global__ __launch_bounds__(256)
void wt_k(const float* __restrict__ W, u16* __restrict__ WT, int K, int N,
          long zSrc, long zDst){
  __shared__ float Ls[64][65];
  W  += (long)blockIdx.z * zSrc;
  WT += (long)blockIdx.z * zDst;
  const int k0 = blockIdx.x * 64, n0 = blockIdx.y * 64;
  const int t = threadIdx.x;
  const int cr = (t & 15) * 4, rr0 = t >> 4;
#pragma unroll
  for (int rr = 0; rr < 4; rr++){
    int row = rr0 + rr * 16;
    const float* wp = W + (size_t)(k0 + row) * N + n0 + cr;
#pragma unroll
    for (int j = 0; j < 4; j++)
      Ls[row][cr + j] = (n0 + cr + j < N) ? wp[j] : 0.f;
  }
  __syncthreads();
  const int nrow = t >> 2, kc = (t & 3) * 16;
  const bool valid = (n0 + nrow) < N;
  u16 buf[16];
#pragma unroll
  for (int j = 0; j < 16; j++)
    buf[j] = valid ? f2bf(Ls[kc + j][nrow]) : (u16)0;
  u16* out = WT + (size_t)(n0 + nrow) * K + k0 + kc;
  ((uint4*)out)[0] = ((uint4*)buf)[0];
  ((uint4*)out)[1] = ((uint4*)buf)[1];
}

// concat QKV biases: out[l][1536] = [bq[l] | bk[l] | bv[l]]
__global__ __launch_bounds__(256)
void qkvbias_k(const float* __restrict__ bq, const float* __restrict__ bk,
               const float* __restrict__ bv, float* __restrict__ out){
  int i = blockIdx.x * 256 + threadIdx.x;
  if (i < NLAYER * 1536){
    int l = i / 1536, c = i - l * 1536;
    float v = (c < 512) ? bq[l * 512 + c]
            : (c < 1024) ? bk[l * 512 + c - 512]
                         : bv[l * 512 + c - 1024];
    out[i] = v;
  }
}

// ---------- MFMA GEMM ----------
// C[M,N] = A[M,K] @ B + epilogue.  A bf16 row-major [M][K] (lda).
// B pre-transposed bf16 [Npad][K] (ldb=K). M mult 64, K mult 32. N guarded.
template<bool GELU, bool RES, bool BIAS, bool OUTBF>
__global__ __launch_bounds__(256)
void mgemm(const u16* __restrict__ A, const u16* __restrict__ B,
           const float* __restrict__ bias, const float* __restrict__ res,
           void* __restrict__ Cout, int M, int N, int K,
           int lda, int ldb, int ldc)
{
  __shared__ u16 As[64][40];
  __shared__ u16 Bs[64][40];
  const int tid = threadIdx.x;
  const int row0 = blockIdx.y * 64, n0 = blockIdx.x * 64;
  const int w = tid >> 6, lane = tid & 63, m = lane & 15, quad = lane >> 4;

  f32x4 acc[4];
#pragma unroll
  for (int c = 0; c < 4; c++) acc[c] = (f32x4){0.f, 0.f, 0.f, 0.f};

  const int ar = tid >> 2, akc = (tid & 3) * 8;

  for (int k0 = 0; k0 < K; k0 += 32){
    *(uint4*)&As[ar][akc] = *(const uint4*)&A[(long)(row0 + ar) * lda + k0 + akc];
    *(uint4*)&Bs[ar][akc] = *(const uint4*)&B[(long)(n0 + ar) * ldb + k0 + akc];
    __syncthreads();
    short8 a = *(const short8*)&As[w * 16 + m][quad * 8];
#pragma unroll
    for (int c = 0; c < 4; c++){
      short8 b = *(const short8*)&Bs[c * 16 + m][quad * 8];
      acc[c] = __builtin_amdgcn_mfma_f32_16x16x32_bf16(a, b, acc[c], 0, 0, 0);
    }
    __syncthreads();
  }

#pragma unroll
  for (int c = 0; c < 4; c++){
    int col = n0 + c * 16 + m;
    if (col < N){
#pragma unroll
      for (int r = 0; r < 4; r++){
        int row = row0 + w * 16 + quad * 4 + r;
        float val = acc[c][r];
        if (BIAS) val += bias[col];
        if (RES)  val += res[(long)row * ldc + col];
        if (GELU) val = 0.5f * val * (1.f + erff(val * 0.70710678118f));
        if (OUTBF) ((u16*)Cout)[(long)row * ldc + col] = f2bf(val);
        else      ((float*)Cout)[(long)row * ldc + col] = val;
      }
    }
  }
}

// ---------- LayerNorm: fp32 in, bf16 out ----------
__global__ __launch_bounds__(256)
void ln_k(const float* __restrict__ x, const float* __restrict__ g,
          const float* __restrict__ b, u16* __restrict__ out)
{
  __shared__ float red[256];
  const int r = blockIdx.x, tid = threadIdx.x;
  const float* xr = x + (size_t)r * DM;
  float v0 = xr[tid], v1 = xr[tid + 256];
  float mean = block_sum(v0 + v1, red) * (1.f / DM);
  float d0 = v0 - mean, d1 = v1 - mean;
  float var = block_sum(d0 * d0 + d1 * d1, red) * (1.f / DM);
  float inv = rsqrtf(var + 1e-5f);
  out[(size_t)r * DM + tid]       = f2bf(d0 * inv * g[tid]       + b[tid]);
  out[(size_t)r * DM + tid + 256] = f2bf(d1 * inv * g[tid + 256] + b[tid + 256]);
}

// ---------- flash attention: QK^T*scale + Toeplitz rel, online softmax, PV ----------
// qkv: [1024][1536] bf16 rows = [q | k | v]; o: [1024][512] bf16.
// Block = (64 q-rows, 1 head); 4 waves, wave w owns q-rows w*16..w*16+15.
__global__ __launch_bounds__(256)
void flash_k(const u16* __restrict__ qkv, const u16* __restrict__ ErB,
             u16* __restrict__ o)
{
  __shared__ u16 Qs[64][72];
  __shared__ u16 Ks[64][72];
  __shared__ u16 VsT[64][72];   // [hd_col][t]
  __shared__ u16 Es[128][72];
  __shared__ u16 Ts[64][136];   // T gather buffer (bf16)
  __shared__ u16 Ps[64][72];    // P tile (bf16)

  const int tid = threadIdx.x;
  const int s0 = blockIdx.x * 64, hh = blockIdx.y;
  const int w = tid >> 6, lane = tid & 63, m = lane & 15, quad = lane >> 4;

  // stage Q once
  {
    const int r = tid >> 2, kc = (tid & 3) * 16;
    const u16* qp = qkv + (size_t)(s0 + r) * 1536 + hh * HD + kc;
    *(uint4*)&Qs[r][kc]     = *(const uint4*)&qp[0];
    *(uint4*)&Qs[r][kc + 8] = *(const uint4*)&qp[8];
  }
  __syncthreads();

  const short8 a0 = *(const short8*)&Qs[w * 16 + m][quad * 8];
  const short8 a1 = *(const short8*)&Qs[w * 16 + m][32 + quad * 8];

  f32x4 accO[4];
#pragma unroll
  for (int c = 0; c < 4; c++) accO[c] = (f32x4){0.f, 0.f, 0.f, 0.f};
  float mrun[4], lrun[4];
#pragma unroll
  for (int r = 0; r < 4; r++){ mrun[r] = -1e30f; lrun[r] = 0.f; }

  for (int t0 = 0; t0 < SEQ; t0 += 64){
    __syncthreads();  // prior iteration's reads of Ks/VsT/Es/Ps complete
    // ---- stage K tile, V^T tile, Er band ----
    {
      const int r = tid >> 2, kc = (tid & 3) * 16;
      const u16* kp = qkv + (size_t)(t0 + r) * 1536 + 512 + hh * HD + kc;
      *(uint4*)&Ks[r][kc]     = *(const uint4*)&kp[0];
      *(uint4*)&Ks[r][kc + 8] = *(const uint4*)&kp[8];
      const u16* vp = qkv + (size_t)(t0 + r) * 1536 + 1024 + hh * HD + kc;
      uint4 v0 = *(const uint4*)&vp[0];
      uint4 v1 = *(const uint4*)&vp[8];
      const u16* pv0 = (const u16*)&v0;
      const u16* pv1 = (const u16*)&v1;
#pragma unroll
      for (int j = 0; j < 8; j++) VsT[kc + j][r]     = pv0[j];
#pragma unroll
      for (int j = 0; j < 8; j++) VsT[kc + 8 + j][r] = pv1[j];
      const int rb = s0 - t0 + 960;   // band rows rb..rb+126 in [0,2046]
      for (int idx = tid; idx < 127 * 8; idx += 256){
        int er = idx >> 3, ekc = (idx & 7) * 8;
        *(uint4*)&Es[er][ekc] = *(const uint4*)&ErB[(size_t)(rb + er) * HD + ekc];
      }
      if (tid < 8){ uint4 z = {0,0,0,0}; *(uint4*)&Es[127][tid * 8] = z; }
    }
    __syncthreads();

    // ---- QK^T and T = Q @ Er_band^T ----
    f32x4 qk[4], tt[8];
#pragma unroll
    for (int c = 0; c < 4; c++) qk[c] = (f32x4){0.f,0.f,0.f,0.f};
#pragma unroll
    for (int c = 0; c < 8; c++) tt[c] = (f32x4){0.f,0.f,0.f,0.f};
#pragma unroll
    for (int c = 0; c < 4; c++){
      short8 b0 = *(const short8*)&Ks[c * 16 + m][quad * 8];
      short8 b1 = *(const short8*)&Ks[c * 16 + m][32 + quad * 8];
      qk[c] = __builtin_amdgcn_mfma_f32_16x16x32_bf16(a0, b0, qk[c], 0, 0, 0);
      qk[c] = __builtin_amdgcn_mfma_f32_16x16x32_bf16(a1, b1, qk[c], 0, 0, 0);
    }
#pragma unroll
    for (int c = 0; c < 8; c++){
      short8 b0 = *(const short8*)&Es[c * 16 + m][quad * 8];
      short8 b1 = *(const short8*)&Es[c * 16 + m][32 + quad * 8];
      tt[c] = __builtin_amdgcn_mfma_f32_16x16x32_bf16(a0, b0, tt[c], 0, 0, 0);
      tt[c] = __builtin_amdgcn_mfma_f32_16x16x32_bf16(a1, b1, tt[c], 0, 0, 0);
    }
#pragma unroll
    for (int c = 0; c < 8; c++)
#pragma unroll
      for (int r = 0; r < 4; r++)
        Ts[w * 16 + quad * 4 + r][c * 16 + m] = f2bf(tt[c][r]);
    __syncthreads();

    // ---- combine + online softmax ----
    float sv[4][4];
#pragma unroll
    for (int c = 0; c < 4; c++){
      int j = c * 16 + m;
#pragma unroll
      for (int r = 0; r < 4; r++){
        int i = w * 16 + quad * 4 + r;
        sv[c][r] = qk[c][r] * 0.125f + bf2f(Ts[i][i - j + 63]);
      }
    }
    float alpha[4];
#pragma unroll
    for (int r = 0; r < 4; r++){
      float rmax = fmaxf(fmaxf(sv[0][r], sv[1][r]), fmaxf(sv[2][r], sv[3][r]));
#pragma unroll
      for (int off = 1; off < 16; off <<= 1)
        rmax = fmaxf(rmax, __shfl_xor(rmax, off));
      float mnew = fmaxf(mrun[r], rmax);
      alpha[r] = __expf(mrun[r] - mnew);
      mrun[r] = mnew;
      float rsum = 0.f;
#pragma unroll
      for (int c = 0; c < 4; c++){
        float pv = __expf(sv[c][r] - mnew);
        sv[c][r] = pv;
        rsum += pv;
      }
#pragma unroll
      for (int off = 1; off < 16; off <<= 1)
        rsum += __shfl_xor(rsum, off);
      lrun[r] = lrun[r] * alpha[r] + rsum;
    }
#pragma unroll
    for (int c = 0; c < 4; c++)
#pragma unroll
      for (int r = 0; r < 4; r++)
        accO[c][r] *= alpha[r];
    // P -> LDS (A-operand layout source)
#pragma unroll
    for (int c = 0; c < 4; c++)
#pragma unroll
      for (int r = 0; r < 4; r++)
        Ps[w * 16 + quad * 4 + r][c * 16 + m] = f2bf(sv[c][r]);
    __syncthreads();

    // ---- PV ----
    short8 pa0 = *(const short8*)&Ps[w * 16 + m][quad * 8];
    short8 pa1 = *(const short8*)&Ps[w * 16 + m][32 + quad * 8];
#pragma unroll
    for (int c = 0; c < 4; c++){
      short8 b0 = *(const short8*)&VsT[c * 16 + m][quad * 8];
      short8 b1 = *(const short8*)&VsT[c * 16 + m][32 + quad * 8];
      accO[c] = __builtin_amdgcn_mfma_f32_16x16x32_bf16(pa0, b0, accO[c], 0, 0, 0);
      accO[c] = __builtin_amdgcn_mfma_f32_16x16x32_bf16(pa1, b1, accO[c], 0, 0, 0);
    }
  }

  // ---- normalize + store ----
#pragma unroll
  for (int c = 0; c < 4; c++){
    int col = hh * HD + c * 16 + m;
#pragma unroll
    for (int r = 0; r < 4; r++){
      int row = s0 + w * 16 + quad * 4 + r;
      o[(size_t)row * DM + col] = f2bf(accO[c][r] / lrun[r]);
    }
  }
}

extern "C" void kernel_launch(void* const* d_in, const int* in_sizes, int n_in,
                              void* d_out, int out_size, void* d_ws, size_t ws_size,
                              hipStream_t stream) {
  const float* x     = (const float*)d_in[0];
  const float* emb_W = (const float*)d_in[1];
  const float* emb_b = (const float*)d_in[2];
  const float* Wq    = (const float*)d_in[3];
  const float* bq    = (const float*)d_in[4];
  const float* Wk    = (const float*)d_in[5];
  const float* bk    = (const float*)d_in[6];
  const float* Wv    = (const float*)d_in[7];
  const float* bv    = (const float*)d_in[8];
  const float* Wo    = (const float*)d_in[9];
  const float* bo    = (const float*)d_in[10];
  const float* Er    = (const float*)d_in[11];
  const float* ln1_g = (const float*)d_in[12];
  const float* ln1_b = (const float*)d_in[13];
  const float* W1    = (const float*)d_in[14];
  const float* b1    = (const float*)d_in[15];
  const float* W2    = (const float*)d_in[16];
  const float* b2    = (const float*)d_in[17];
  const float* ln2_g = (const float*)d_in[18];
  const float* ln2_b = (const float*)d_in[19];
  const float* lnf_g = (const float*)d_in[20];
  const float* lnf_b = (const float*)d_in[21];
  const float* Wi    = (const float*)d_in[22];
  const float* bi    = (const float*)d_in[23];
  const float* Wf    = (const float*)d_in[24];
  const float* bfin  = (const float*)d_in[25];

  // ---- workspace carve ----
  u16* p = (u16*)d_ws;
  u16* xb    = p; p += SEQ * DIN;
  u16* embT  = p; p += DM * DIN;
  u16* wqkvT = p; p += (size_t)NLAYER * 1536 * DM;    // [l][1536][512]
  u16* woT   = p; p += (size_t)NLAYER * DM * DM;
  u16* w1T   = p; p += (size_t)NLAYER * DFF * DM;
  u16* w2T   = p; p += (size_t)NLAYER * DM * DFF;
  u16* wiT   = p; p += (size_t)(2 * DM) * DM;
  u16* wfT   = p; p += (size_t)448 * (2 * DM);
  u16* erB   = p; p += (size_t)NLAYER * ERROWS * HD;
  u16* nb    = p; p += SEQ * DM;
  u16* qkvb  = p; p += (size_t)SEQ * 1536;
  u16* ob    = p; p += SEQ * DM;
  u16* mid   = p; p += (size_t)SEQ * DFF;
  float* qkvbias = (float*)p;
  float* hb = qkvbias + NLAYER * 1536;

  dim3 blk(256);

  // ---- one-time conversions ----
  cvt_k<<<SEQ * DIN / 4 / 256, blk, 0, stream>>>(x, xb, SEQ * DIN);
  cvt_k<<<(NLAYER * ERROWS * HD / 4 + 255) / 256, blk, 0, stream>>>(Er, erB, NLAYER * ERROWS * HD);
  qkvbias_k<<<(NLAYER * 1536 + 255) / 256, blk, 0, stream>>>(bq, bk, bv, qkvbias);
  wt_k<<<dim3(2, 8, 1), blk, 0, stream>>>(emb_W, embT, DIN, DM, 0, 0);
  wt_k<<<dim3(8, 8, NLAYER), blk, 0, stream>>>(Wq, wqkvT,               DM, DM, (long)DM*DM, (long)1536*DM);
  wt_k<<<dim3(8, 8, NLAYER), blk, 0, stream>>>(Wk, wqkvT + 512 * DM,    DM, DM, (long)DM*DM, (long)1536*DM);
  wt_k<<<dim3(8, 8, NLAYER), blk, 0, stream>>>(Wv, wqkvT + 1024 * DM,   DM, DM, (long)DM*DM, (long)1536*DM);
  wt_k<<<dim3(8, 8, NLAYER), blk, 0, stream>>>(Wo, woT, DM, DM, (long)DM*DM, (long)DM*DM);
  wt_k<<<dim3(8, 32, NLAYER), blk, 0, stream>>>(W1, w1T, DM, DFF, (long)DM*DFF, (long)DFF*DM);
  wt_k<<<dim3(32, 8, NLAYER), blk, 0, stream>>>(W2, w2T, DFF, DM, (long)DFF*DM, (long)DM*DFF);
  wt_k<<<dim3(8, 16, 1), blk, 0, stream>>>(Wi, wiT, DM, 2 * DM, 0, 0);
  wt_k<<<dim3(16, 7, 1), blk, 0, stream>>>(Wf, wfT, 2 * DM, DOUT, 0, 0);

  dim3 g512(8, 16), gqkv(24, 16), gff(32, 16), gwi(16, 16), gout(7, 16);
  dim3 gfl(16, NH);

  // ---- embedding ----
  mgemm<false, false, true, false><<<g512, blk, 0, stream>>>(
      xb, embT, emb_b, nullptr, hb, SEQ, DM, DIN, DIN, DIN, DM);

  for (int l = 0; l < NLAYER; l++) {
    const u16* wqkvT_l = wqkvT + (size_t)l * 1536 * DM;
    const u16* woT_l   = woT + (size_t)l * DM * DM;
    const u16* w1T_l   = w1T + (size_t)l * DFF * DM;
    const u16* w2T_l   = w2T + (size_t)l * DM * DFF;
    const u16* erB_l   = erB + (size_t)l * ERROWS * HD;

    ln_k<<<SEQ, blk, 0, stream>>>(hb, ln1_g + l * DM, ln1_b + l * DM, nb);
    mgemm<false, false, true, true><<<gqkv, blk, 0, stream>>>(
        nb, wqkvT_l, qkvbias + l * 1536, nullptr, qkvb, SEQ, 1536, DM, DM, DM, 1536);

    flash_k<<<gfl, blk, 0, stream>>>(qkvb, erB_l, ob);

    mgemm<false, true, true, false><<<g512, blk, 0, stream>>>(
        ob, woT_l, bo + l * DM, hb, hb, SEQ, DM, DM, DM, DM, DM);

    ln_k<<<SEQ, blk, 0, stream>>>(hb, ln2_g + l * DM, ln2_b + l * DM, nb);
    mgemm<true, false, true, true><<<gff, blk, 0, stream>>>(
        nb, w1T_l, b1 + l * DFF, nullptr, mid, SEQ, DFF, DM, DM, DM, DFF);
    mgemm<false, true, true, false><<<g512, blk, 0, stream>>>(
        mid, w2T_l, b2 + l * DM, hb, hb, SEQ, DM, DFF, DFF, DFF, DM);
  }

  ln_k<<<SEQ, blk, 0, stream>>>(hb, lnf_g, lnf_b, nb);
  mgemm<true, false, true, true><<<gwi, blk, 0, stream>>>(
      nb, wiT, bi, nullptr, mid, SEQ, 2 * DM, DM, DM, DM, 2 * DM);
  mgemm<false, false, true, false><<<gout, blk, 0, stream>>>(
      mid, wfT, bfin, nullptr, (float*)d_out, SEQ, DOUT, 2 * DM, 2 * DM, 2 * DM, DOUT);
}

// Round 6
// 587.685 us; speedup vs baseline: 11.6011x; 1.2030x over previous
//
#include <hip/hip_runtime.h>
#include <hip/hip_bf16.h>
#include <math.h>

// Problem constants (B=1)
#define SEQ 1024
#define DM 512
#define NH 8
#define HD 64
#define NLAYER 4
#define DIN 128
#define DFF 2048
#define DOUT 390
#define ERROWS 2047  // 2*MAXS-1
#define NSPLIT 4     // flash split-K factor (t-range quarters)

using u16 = unsigned short;
typedef __attribute__((ext_vector_type(8))) short short8;
typedef __attribute__((ext_vector_type(4))) float f32x4;

__device__ inline u16 f2bf(float f){
  __hip_bfloat16 h = __float2bfloat16(f);
  return *(u16*)&h;
}
__device__ inline float bf2f(u16 u){
  __hip_bfloat16 h; *(u16*)&h = u;
  return __bfloat162float(h);
}

__device__ inline float block_sum(float v, float* red){
  int tid = threadIdx.x;
  red[tid] = v; __syncthreads();
  for (int s = 128; s > 0; s >>= 1){
    if (tid < s) red[tid] += red[tid + s];
    __syncthreads();
  }
  float r = red[0]; __syncthreads();
  return r;
}

// ---------- weight prep ----------
__global__ __launch_bounds__(256)
void cvt_k(const float* __restrict__ src, u16* __restrict__ dst, int n){
  int i = (blockIdx.x * 256 + threadIdx.x) * 4;
  if (i < n){
    float4 v = *(const float4*)(src + i);
    dst[i+0] = f2bf(v.x); dst[i+1] = f2bf(v.y);
    dst[i+2] = f2bf(v.z); dst[i+3] = f2bf(v.w);
  }
}

// transpose + convert: WT[n][k] = bf16(W[k][n]); K mult 64; rows n>=N zero-filled
__global__ __launch_bounds__(256)
void wt_k(const float* __restrict__ W, u16* __restrict__ WT, int K, int N,
          long zSrc, long zDst){
  __shared__ float Ls[64][65];
  W  += (long)blockIdx.z * zSrc;
  WT += (long)blockIdx.z * zDst;
  const int k0 = blockIdx.x * 64, n0 = blockIdx.y * 64;
  const int t = threadIdx.x;
  const int cr = (t & 15) * 4, rr0 = t >> 4;
#pragma unroll
  for (int rr = 0; rr < 4; rr++){
    int row = rr0 + rr * 16;
    const float* wp = W + (size_t)(k0 + row) * N + n0 + cr;
#pragma unroll
    for (int j = 0; j < 4; j++)
      Ls[row][cr + j] = (n0 + cr + j < N) ? wp[j] : 0.f;
  }
  __syncthreads();
  const int nrow = t >> 2, kc = (t & 3) * 16;
  const bool valid = (n0 + nrow) < N;
  u16 buf[16];
#pragma unroll
  for (int j = 0; j < 16; j++)
    buf[j] = valid ? f2bf(Ls[kc + j][nrow]) : (u16)0;
  u16* out = WT + (size_t)(n0 + nrow) * K + k0 + kc;
  ((uint4*)out)[0] = ((uint4*)buf)[0];
  ((uint4*)out)[1] = ((uint4*)buf)[1];
}

// concat QKV biases: out[l][1536] = [bq[l] | bk[l] | bv[l]]
__global__ __launch_bounds__(256)
void qkvbias_k(const float* __restrict__ bq, const float* __restrict__ bk,
               const float* __restrict__ bv, float* __restrict__ out){
  int i = blockIdx.x * 256 + threadIdx.x;
  if (i < NLAYER * 1536){
    int l = i / 1536, c = i - l * 1536;
    float v = (c < 512) ? bq[l * 512 + c]
            : (c < 1024) ? bk[l * 512 + c - 512]
                         : bv[l * 512 + c - 1024];
    out[i] = v;
  }
}

// ---------- MFMA GEMM ----------
// C[M,N] = A[M,K] @ B + epilogue.  A bf16 [M][K] (lda); B pre-transposed [Npad][K].
template<bool GELU, bool RES, bool BIAS, bool OUTBF>
__global__ __launch_bounds__(256)
void mgemm(const u16* __restrict__ A, const u16* __restrict__ B,
           const float* __restrict__ bias, const float* __restrict__ res,
           void* __restrict__ Cout, int M, int N, int K,
           int lda, int ldb, int ldc)
{
  __shared__ u16 As[64][40];
  __shared__ u16 Bs[64][40];
  const int tid = threadIdx.x;
  const int row0 = blockIdx.y * 64, n0 = blockIdx.x * 64;
  const int w = tid >> 6, lane = tid & 63, m = lane & 15, quad = lane >> 4;

  f32x4 acc[4];
#pragma unroll
  for (int c = 0; c < 4; c++) acc[c] = (f32x4){0.f, 0.f, 0.f, 0.f};

  const int ar = tid >> 2, akc = (tid & 3) * 8;

  for (int k0 = 0; k0 < K; k0 += 32){
    *(uint4*)&As[ar][akc] = *(const uint4*)&A[(long)(row0 + ar) * lda + k0 + akc];
    *(uint4*)&Bs[ar][akc] = *(const uint4*)&B[(long)(n0 + ar) * ldb + k0 + akc];
    __syncthreads();
    short8 a = *(const short8*)&As[w * 16 + m][quad * 8];
#pragma unroll
    for (int c = 0; c < 4; c++){
      short8 b = *(const short8*)&Bs[c * 16 + m][quad * 8];
      acc[c] = __builtin_amdgcn_mfma_f32_16x16x32_bf16(a, b, acc[c], 0, 0, 0);
    }
    __syncthreads();
  }

#pragma unroll
  for (int c = 0; c < 4; c++){
    int col = n0 + c * 16 + m;
    if (col < N){
#pragma unroll
      for (int r = 0; r < 4; r++){
        int row = row0 + w * 16 + quad * 4 + r;
        float val = acc[c][r];
        if (BIAS) val += bias[col];
        if (RES)  val += res[(long)row * ldc + col];
        if (GELU) val = 0.5f * val * (1.f + erff(val * 0.70710678118f));
        if (OUTBF) ((u16*)Cout)[(long)row * ldc + col] = f2bf(val);
        else      ((float*)Cout)[(long)row * ldc + col] = val;
      }
    }
  }
}

// ---------- LayerNorm: fp32 in, bf16 out ----------
__global__ __launch_bounds__(256)
void ln_k(const float* __restrict__ x, const float* __restrict__ g,
          const float* __restrict__ b, u16* __restrict__ out)
{
  __shared__ float red[256];
  const int r = blockIdx.x, tid = threadIdx.x;
  const float* xr = x + (size_t)r * DM;
  float v0 = xr[tid], v1 = xr[tid + 256];
  float mean = block_sum(v0 + v1, red) * (1.f / DM);
  float d0 = v0 - mean, d1 = v1 - mean;
  float var = block_sum(d0 * d0 + d1 * d1, red) * (1.f / DM);
  float inv = rsqrtf(var + 1e-5f);
  out[(size_t)r * DM + tid]       = f2bf(d0 * inv * g[tid]       + b[tid]);
  out[(size_t)r * DM + tid + 256] = f2bf(d1 * inv * g[tid + 256] + b[tid + 256]);
}

// ---------- split-K flash attention ----------
// Block = (64 q-rows, head, split); split sp covers t in [sp*256, sp*256+256).
// Emits unnormalized partial O (fp32) + per-row (m, l).
__global__ __launch_bounds__(256)
void flash_k(const u16* __restrict__ qkv, const u16* __restrict__ ErB,
             float* __restrict__ Op, float* __restrict__ ml)
{
  __shared__ u16 Qs[64][72];
  __shared__ u16 Ks[64][72];
  __shared__ u16 VsT[64][72];   // [hd_col][t]
  __shared__ u16 Es[128][72];
  __shared__ u16 Ts[64][136];   // T gather buffer (bf16)
  __shared__ u16 Ps[64][72];    // P tile (bf16)

  const int tid = threadIdx.x;
  const int s0 = blockIdx.x * 64, hh = blockIdx.y, sp = blockIdx.z;
  const int w = tid >> 6, lane = tid & 63, m = lane & 15, quad = lane >> 4;

  // stage Q once
  {
    const int r = tid >> 2, kc = (tid & 3) * 16;
    const u16* qp = qkv + (size_t)(s0 + r) * 1536 + hh * HD + kc;
    *(uint4*)&Qs[r][kc]     = *(const uint4*)&qp[0];
    *(uint4*)&Qs[r][kc + 8] = *(const uint4*)&qp[8];
  }
  __syncthreads();

  const short8 a0 = *(const short8*)&Qs[w * 16 + m][quad * 8];
  const short8 a1 = *(const short8*)&Qs[w * 16 + m][32 + quad * 8];

  f32x4 accO[4];
#pragma unroll
  for (int c = 0; c < 4; c++) accO[c] = (f32x4){0.f, 0.f, 0.f, 0.f};
  float mrun[4], lrun[4];
#pragma unroll
  for (int r = 0; r < 4; r++){ mrun[r] = -1e30f; lrun[r] = 0.f; }

  const int tbeg = sp * (SEQ / NSPLIT), tend = tbeg + SEQ / NSPLIT;
  for (int t0 = tbeg; t0 < tend; t0 += 64){
    __syncthreads();  // prior iteration's reads of Ks/VsT/Es/Ps complete
    // ---- stage K tile, V^T tile, Er band ----
    {
      const int r = tid >> 2, kc = (tid & 3) * 16;
      const u16* kp = qkv + (size_t)(t0 + r) * 1536 + 512 + hh * HD + kc;
      *(uint4*)&Ks[r][kc]     = *(const uint4*)&kp[0];
      *(uint4*)&Ks[r][kc + 8] = *(const uint4*)&kp[8];
      const u16* vp = qkv + (size_t)(t0 + r) * 1536 + 1024 + hh * HD + kc;
      uint4 v0 = *(const uint4*)&vp[0];
      uint4 v1 = *(const uint4*)&vp[8];
      const u16* pv0 = (const u16*)&v0;
      const u16* pv1 = (const u16*)&v1;
#pragma unroll
      for (int j = 0; j < 8; j++) VsT[kc + j][r]     = pv0[j];
#pragma unroll
      for (int j = 0; j < 8; j++) VsT[kc + 8 + j][r] = pv1[j];
      const int rb = s0 - t0 + 960;   // band rows rb..rb+126 in [0,2046]
      for (int idx = tid; idx < 127 * 8; idx += 256){
        int er = idx >> 3, ekc = (idx & 7) * 8;
        *(uint4*)&Es[er][ekc] = *(const uint4*)&ErB[(size_t)(rb + er) * HD + ekc];
      }
      if (tid < 8){ uint4 z = {0,0,0,0}; *(uint4*)&Es[127][tid * 8] = z; }
    }
    __syncthreads();

    // ---- QK^T and T = Q @ Er_band^T ----
    f32x4 qk[4], tt[8];
#pragma unroll
    for (int c = 0; c < 4; c++) qk[c] = (f32x4){0.f,0.f,0.f,0.f};
#pragma unroll
    for (int c = 0; c < 8; c++) tt[c] = (f32x4){0.f,0.f,0.f,0.f};
#pragma unroll
    for (int c = 0; c < 4; c++){
      short8 b0 = *(const short8*)&Ks[c * 16 + m][quad * 8];
      short8 b1 = *(const short8*)&Ks[c * 16 + m][32 + quad * 8];
      qk[c] = __builtin_amdgcn_mfma_f32_16x16x32_bf16(a0, b0, qk[c], 0, 0, 0);
      qk[c] = __builtin_amdgcn_mfma_f32_16x16x32_bf16(a1, b1, qk[c], 0, 0, 0);
    }
#pragma unroll
    for (int c = 0; c < 8; c++){
      short8 b0 = *(const short8*)&Es[c * 16 + m][quad * 8];
      short8 b1 = *(const short8*)&Es[c * 16 + m][32 + quad * 8];
      tt[c] = __builtin_amdgcn_mfma_f32_16x16x32_bf16(a0, b0, tt[c], 0, 0, 0);
      tt[c] = __builtin_amdgcn_mfma_f32_16x16x32_bf16(a1, b1, tt[c], 0, 0, 0);
    }
#pragma unroll
    for (int c = 0; c < 8; c++)
#pragma unroll
      for (int r = 0; r < 4; r++)
        Ts[w * 16 + quad * 4 + r][c * 16 + m] = f2bf(tt[c][r]);
    __syncthreads();

    // ---- combine + online softmax ----
    float sv[4][4];
#pragma unroll
    for (int c = 0; c < 4; c++){
      int j = c * 16 + m;
#pragma unroll
      for (int r = 0; r < 4; r++){
        int i = w * 16 + quad * 4 + r;
        sv[c][r] = qk[c][r] * 0.125f + bf2f(Ts[i][i - j + 63]);
      }
    }
    float alpha[4];
#pragma unroll
    for (int r = 0; r < 4; r++){
      float rmax = fmaxf(fmaxf(sv[0][r], sv[1][r]), fmaxf(sv[2][r], sv[3][r]));
#pragma unroll
      for (int off = 1; off < 16; off <<= 1)
        rmax = fmaxf(rmax, __shfl_xor(rmax, off));
      float mnew = fmaxf(mrun[r], rmax);
      alpha[r] = __expf(mrun[r] - mnew);
      mrun[r] = mnew;
      float rsum = 0.f;
#pragma unroll
      for (int c = 0; c < 4; c++){
        float pv = __expf(sv[c][r] - mnew);
        sv[c][r] = pv;
        rsum += pv;
      }
#pragma unroll
      for (int off = 1; off < 16; off <<= 1)
        rsum += __shfl_xor(rsum, off);
      lrun[r] = lrun[r] * alpha[r] + rsum;
    }
#pragma unroll
    for (int c = 0; c < 4; c++)
#pragma unroll
      for (int r = 0; r < 4; r++)
        accO[c][r] *= alpha[r];
    // P -> LDS (A-operand layout source)
#pragma unroll
    for (int c = 0; c < 4; c++)
#pragma unroll
      for (int r = 0; r < 4; r++)
        Ps[w * 16 + quad * 4 + r][c * 16 + m] = f2bf(sv[c][r]);
    __syncthreads();

    // ---- PV ----
    short8 pa0 = *(const short8*)&Ps[w * 16 + m][quad * 8];
    short8 pa1 = *(const short8*)&Ps[w * 16 + m][32 + quad * 8];
#pragma unroll
    for (int c = 0; c < 4; c++){
      short8 b0 = *(const short8*)&VsT[c * 16 + m][quad * 8];
      short8 b1 = *(const short8*)&VsT[c * 16 + m][32 + quad * 8];
      accO[c] = __builtin_amdgcn_mfma_f32_16x16x32_bf16(pa0, b0, accO[c], 0, 0, 0);
      accO[c] = __builtin_amdgcn_mfma_f32_16x16x32_bf16(pa1, b1, accO[c], 0, 0, 0);
    }
  }

  // ---- store partials ----
  const long base = ((long)sp * NH + hh) * SEQ;
#pragma unroll
  for (int c = 0; c < 4; c++){
#pragma unroll
    for (int r = 0; r < 4; r++){
      int row = s0 + w * 16 + quad * 4 + r;
      Op[(base + row) * HD + c * 16 + m] = accO[c][r];
    }
  }
  if (m == 0){
#pragma unroll
    for (int r = 0; r < 4; r++){
      int row = s0 + w * 16 + quad * 4 + r;
      ml[(base + row) * 2 + 0] = mrun[r];
      ml[(base + row) * 2 + 1] = lrun[r];
    }
  }
}

// combine split partials: o[s][h*64+c] = sum_sp w_sp*Op / sum_sp w_sp*l_sp
__global__ __launch_bounds__(256)
void fcomb_k(const float* __restrict__ Op, const float* __restrict__ ml,
             u16* __restrict__ o)
{
  const int s = blockIdx.x, tid = threadIdx.x;
  const int hh = tid >> 5, c0 = (tid & 31) * 2;
  float mm[NSPLIT], ll[NSPLIT];
#pragma unroll
  for (int sp = 0; sp < NSPLIT; sp++){
    long b = (((long)sp * NH + hh) * SEQ + s) * 2;
    mm[sp] = ml[b]; ll[sp] = ml[b + 1];
  }
  float ms = fmaxf(fmaxf(mm[0], mm[1]), fmaxf(mm[2], mm[3]));
  float o0 = 0.f, o1 = 0.f, lsum = 0.f;
#pragma unroll
  for (int sp = 0; sp < NSPLIT; sp++){
    float wsp = __expf(mm[sp] - ms);
    lsum += wsp * ll[sp];
    const float* op = Op + (((long)sp * NH + hh) * SEQ + s) * HD + c0;
    o0 += wsp * op[0];
    o1 += wsp * op[1];
  }
  float inv = 1.f / lsum;
  o[(size_t)s * DM + hh * HD + c0]     = f2bf(o0 * inv);
  o[(size_t)s * DM + hh * HD + c0 + 1] = f2bf(o1 * inv);
}

extern "C" void kernel_launch(void* const* d_in, const int* in_sizes, int n_in,
                              void* d_out, int out_size, void* d_ws, size_t ws_size,
                              hipStream_t stream) {
  const float* x     = (const float*)d_in[0];
  const float* emb_W = (const float*)d_in[1];
  const float* emb_b = (const float*)d_in[2];
  const float* Wq    = (const float*)d_in[3];
  const float* bq    = (const float*)d_in[4];
  const float* Wk    = (const float*)d_in[5];
  const float* bk    = (const float*)d_in[6];
  const float* Wv    = (const float*)d_in[7];
  const float* bv    = (const float*)d_in[8];
  const float* Wo    = (const float*)d_in[9];
  const float* bo    = (const float*)d_in[10];
  const float* Er    = (const float*)d_in[11];
  const float* ln1_g = (const float*)d_in[12];
  const float* ln1_b = (const float*)d_in[13];
  const float* W1    = (const float*)d_in[14];
  const float* b1    = (const float*)d_in[15];
  const float* W2    = (const float*)d_in[16];
  const float* b2    = (const float*)d_in[17];
  const float* ln2_g = (const float*)d_in[18];
  const float* ln2_b = (const float*)d_in[19];
  const float* lnf_g = (const float*)d_in[20];
  const float* lnf_b = (const float*)d_in[21];
  const float* Wi    = (const float*)d_in[22];
  const float* bi    = (const float*)d_in[23];
  const float* Wf    = (const float*)d_in[24];
  const float* bfin  = (const float*)d_in[25];

  // ---- workspace carve ----
  u16* p = (u16*)d_ws;
  u16* xb    = p; p += SEQ * DIN;
  u16* embT  = p; p += DM * DIN;
  u16* wqkvT = p; p += (size_t)NLAYER * 1536 * DM;    // [l][1536][512]
  u16* woT   = p; p += (size_t)NLAYER * DM * DM;
  u16* w1T   = p; p += (size_t)NLAYER * DFF * DM;
  u16* w2T   = p; p += (size_t)NLAYER * DM * DFF;
  u16* wiT   = p; p += (size_t)(2 * DM) * DM;
  u16* wfT   = p; p += (size_t)448 * (2 * DM);
  u16* erB   = p; p += (size_t)NLAYER * ERROWS * HD;
  u16* nb    = p; p += SEQ * DM;
  u16* qkvb  = p; p += (size_t)SEQ * 1536;
  u16* ob    = p; p += SEQ * DM;
  u16* mid   = p; p += (size_t)SEQ * DFF;
  float* qkvbias = (float*)p;
  float* hb  = qkvbias + NLAYER * 1536;
  float* Op  = hb + SEQ * DM;                     // NSPLIT*NH*SEQ*64 fp32 (8 MB)
  float* mlb = Op + (size_t)NSPLIT * NH * SEQ * HD;  // NSPLIT*NH*SEQ*2

  dim3 blk(256);

  // ---- one-time conversions ----
  cvt_k<<<SEQ * DIN / 4 / 256, blk, 0, stream>>>(x, xb, SEQ * DIN);
  cvt_k<<<(NLAYER * ERROWS * HD / 4 + 255) / 256, blk, 0, stream>>>(Er, erB, NLAYER * ERROWS * HD);
  qkvbias_k<<<(NLAYER * 1536 + 255) / 256, blk, 0, stream>>>(bq, bk, bv, qkvbias);
  wt_k<<<dim3(2, 8, 1), blk, 0, stream>>>(emb_W, embT, DIN, DM, 0, 0);
  wt_k<<<dim3(8, 8, NLAYER), blk, 0, stream>>>(Wq, wqkvT,             DM, DM, (long)DM*DM, (long)1536*DM);
  wt_k<<<dim3(8, 8, NLAYER), blk, 0, stream>>>(Wk, wqkvT + 512 * DM,  DM, DM, (long)DM*DM, (long)1536*DM);
  wt_k<<<dim3(8, 8, NLAYER), blk, 0, stream>>>(Wv, wqkvT + 1024 * DM, DM, DM, (long)DM*DM, (long)1536*DM);
  wt_k<<<dim3(8, 8, NLAYER), blk, 0, stream>>>(Wo, woT, DM, DM, (long)DM*DM, (long)DM*DM);
  wt_k<<<dim3(8, 32, NLAYER), blk, 0, stream>>>(W1, w1T, DM, DFF, (long)DM*DFF, (long)DFF*DM);
  wt_k<<<dim3(32, 8, NLAYER), blk, 0, stream>>>(W2, w2T, DFF, DM, (long)DFF*DM, (long)DM*DFF);
  wt_k<<<dim3(8, 16, 1), blk, 0, stream>>>(Wi, wiT, DM, 2 * DM, 0, 0);
  wt_k<<<dim3(16, 7, 1), blk, 0, stream>>>(Wf, wfT, 2 * DM, DOUT, 0, 0);

  dim3 g512(8, 16), gqkv(24, 16), gff(32, 16), gwi(16, 16), gout(7, 16);
  dim3 gfl(16, NH, NSPLIT);

  // ---- embedding ----
  mgemm<false, false, true, false><<<g512, blk, 0, stream>>>(
      xb, embT, emb_b, nullptr, hb, SEQ, DM, DIN, DIN, DIN, DM);

  for (int l = 0; l < NLAYER; l++) {
    const u16* wqkvT_l = wqkvT + (size_t)l * 1536 * DM;
    const u16* woT_l   = woT + (size_t)l * DM * DM;
    const u16* w1T_l   = w1T + (size_t)l * DFF * DM;
    const u16* w2T_l   = w2T + (size_t)l * DM * DFF;
    const u16* erB_l   = erB + (size_t)l * ERROWS * HD;

    ln_k<<<SEQ, blk, 0, stream>>>(hb, ln1_g + l * DM, ln1_b + l * DM, nb);
    mgemm<false, false, true, true><<<gqkv, blk, 0, stream>>>(
        nb, wqkvT_l, qkvbias + l * 1536, nullptr, qkvb, SEQ, 1536, DM, DM, DM, 1536);

    flash_k<<<gfl, blk, 0, stream>>>(qkvb, erB_l, Op, mlb);
    fcomb_k<<<SEQ, blk, 0, stream>>>(Op, mlb, ob);

    mgemm<false, true, true, false><<<g512, blk, 0, stream>>>(
        ob, woT_l, bo + l * DM, hb, hb, SEQ, DM, DM, DM, DM, DM);

    ln_k<<<SEQ, blk, 0, stream>>>(hb, ln2_g + l * DM, ln2_b + l * DM, nb);
    mgemm<true, false, true, true><<<gff, blk, 0, stream>>>(
        nb, w1T_l, b1 + l * DFF, nullptr, mid, SEQ, DFF, DM, DM, DM, DFF);
    mgemm<false, true, true, false><<<g512, blk, 0, stream>>>(
        mid, w2T_l, b2 + l * DM, hb, hb, SEQ, DM, DFF, DFF, DFF, DM);
  }

  ln_k<<<SEQ, blk, 0, stream>>>(hb, lnf_g, lnf_b, nb);
  mgemm<true, false, true, true><<<gwi, blk, 0, stream>>>(
      nb, wiT, bi, nullptr, mid, SEQ, 2 * DM, DM, DM, DM, 2 * DM);
  mgemm<false, false, true, false><<<gout, blk, 0, stream>>>(
      mid, wfT, bfin, nullptr, (float*)d_out, SEQ, DOUT, 2 * DM, 2 * DM, 2 * DM, DOUT);
}